// Round 5
// baseline (1005.864 us; speedup 1.0000x reference)
//
#include <hip/hip_runtime.h>

typedef __attribute__((ext_vector_type(8))) _Float16 half8;
typedef __attribute__((ext_vector_type(4))) _Float16 half4;
typedef __attribute__((ext_vector_type(4))) float floatx4;

#define DI __device__ __forceinline__

// ------------- weight split via LDS transpose: (CO,CI,27) fp32 -> (CO,27,CI) f16 hi/lo, x64 -------------
__global__ __launch_bounds__(256) void wt_split_t(
        const float* __restrict__ w1, _Float16* __restrict__ w1h, _Float16* __restrict__ w1l,
        const float* __restrict__ w2, _Float16* __restrict__ w2h, _Float16* __restrict__ w2l) {
    __shared__ float L[13824];
    const int b = blockIdx.x;
    const int tid = threadIdx.x;
    if (b < 512) {
        const float* src = w1 + (size_t)b * 6912;
        for (int idx = tid; idx < 6912; idx += 256) L[idx] = src[idx] * 64.0f;
        __syncthreads();
        for (int c = tid; c < 864; c += 256) {          // 27 taps x 32 octets
            const int tap = c >> 5, ci0 = (c & 31) * 8;
            half8 h, l;
#pragma unroll
            for (int j = 0; j < 8; ++j) {
                const float x = L[(ci0 + j) * 27 + tap];
                const _Float16 hh = (_Float16)x;
                h[j] = hh; l[j] = (_Float16)(x - (float)hh);
            }
            const size_t off = (size_t)b * 6912 + tap * 256 + ci0;
            *(half8*)&w1h[off] = h;
            *(half8*)&w1l[off] = l;
        }
    } else {
        const float* src = w2 + (size_t)(b - 512) * 13824;
        for (int idx = tid; idx < 13824; idx += 256) L[idx] = src[idx] * 64.0f;
        __syncthreads();
        for (int c = tid; c < 1728; c += 256) {         // 27 taps x 64 octets
            const int tap = c >> 6, ci0 = (c & 63) * 8;
            half8 h, l;
#pragma unroll
            for (int j = 0; j < 8; ++j) {
                const float x = L[(ci0 + j) * 27 + tap];
                const _Float16 hh = (_Float16)x;
                h[j] = hh; l[j] = (_Float16)(x - (float)hh);
            }
            const size_t off = (size_t)(b - 512) * 13824 + tap * 512 + ci0;
            *(half8*)&w2h[off] = h;
            *(half8*)&w2l[off] = l;
        }
    }
}

// ------------- input split via LDS transpose: (256,65536) fp32 -> (65536,256) f16 hi/lo -------------
__global__ __launch_bounds__(256) void in_split(const float* __restrict__ in,
                                                _Float16* __restrict__ oh,
                                                _Float16* __restrict__ ol) {
    __shared__ float T[128 * 65];
    const int hb = blockIdx.x;            // ci half: 0,1
    const int s0 = blockIdx.y * 64;       // spatial tile
    const int tid = threadIdx.x;
    const int cil = tid >> 1, part = tid & 1;
    const float* src = in + (size_t)(hb * 128 + cil) * 65536 + s0 + part * 32;
    float v[32];
#pragma unroll
    for (int q = 0; q < 8; ++q) *(float4*)(v + q * 4) = *(const float4*)(src + q * 4);
#pragma unroll
    for (int j = 0; j < 32; ++j) T[cil * 65 + part * 32 + j] = v[j];
    __syncthreads();
#pragma unroll
    for (int k = 0; k < 4; ++k) {         // 64 sp x 16 octets = 1024 chunks
        const int c = tid + k * 256;
        const int sp = c >> 4, o = c & 15, ci0 = o * 8;
        half8 h, l;
#pragma unroll
        for (int j = 0; j < 8; ++j) {
            const float x = T[(ci0 + j) * 65 + sp];
            const _Float16 hh = (_Float16)x;
            h[j] = hh; l[j] = (_Float16)(x - (float)hh);
        }
        const size_t off = (size_t)(s0 + sp) * 256 + hb * 128 + ci0;
        *(half8*)&oh[off] = h;
        *(half8*)&ol[off] = l;
    }
}

// ------------- conv1: pipelined K-loop (register prefetch), K64/iter, ci-outer tap-inner -------------
__global__ __launch_bounds__(256, 2) void conv1_mfma(
        const _Float16* __restrict__ xh, const _Float16* __restrict__ xl,
        const _Float16* __restrict__ wh, const _Float16* __restrict__ wl,
        const float* __restrict__ b1,
        _Float16* __restrict__ yh, _Float16* __restrict__ yl) {
    __shared__ __align__(16) _Float16 Ah[128 * 64];
    __shared__ __align__(16) _Float16 Al[128 * 64];
    __shared__ __align__(16) _Float16 Bh[128 * 64];
    __shared__ __align__(16) _Float16 Bl[128 * 64];
    const int tid = threadIdx.x;
    const int co_blk = blockIdx.x;      // 0..3
    const int t = blockIdx.y;           // 0..63
    const int h0 = blockIdx.z * 8;      // 0 or 8
    const int wid = tid >> 6, lane = tid & 63;
    const int wm = wid & 1, wn = wid >> 1;
    const int ml = lane & 15, ql = lane >> 4;
    const int cs0 = (ql ^ (ml & 7)) * 8;
    const int cs1 = ((4 + ql) ^ (ml & 7)) * 8;
    // A staging slots: 128 rows x 8 chunks, 4 per thread
    int asl[4]; size_t agof[4];
#pragma unroll
    for (int k = 0; k < 4; ++k) {
        const int s = tid + k * 256;
        const int r = s >> 3, c = s & 7;
        asl[k] = r * 64 + (c ^ (r & 7)) * 8;
        agof[k] = (size_t)r * 6912 + c * 8;
    }
    // B staging: row + 4 contiguous chunks per thread
    const int brow = tid >> 1, bsel = (tid & 1) * 4, br7 = brow & 7;
    const int bh_ = h0 + (brow >> 4), bw_ = brow & 15;
    int bslot[4];
#pragma unroll
    for (int j = 0; j < 4; ++j) bslot[j] = brow * 64 + ((bsel + j) ^ br7) * 8;

    floatx4 zz = {0.f, 0.f, 0.f, 0.f};
    floatx4 acc[4][4];
#pragma unroll
    for (int i = 0; i < 4; ++i)
#pragma unroll
        for (int j = 0; j < 4; ++j) acc[i][j] = zz;

    const size_t wbo = (size_t)co_blk * 128 * 6912;
    const uint4 z4 = make_uint4(0u, 0u, 0u, 0u);
    uint4 rAh[4], rAl[4], rBh[4], rBl[4];

    auto prefetch = [&](int tap, int ci0) {
        const size_t ab = wbo + (size_t)tap * 256 + ci0;
#pragma unroll
        for (int k = 0; k < 4; ++k) {
            rAh[k] = *(const uint4*)(wh + ab + agof[k]);
            rAl[k] = *(const uint4*)(wl + ab + agof[k]);
        }
        const int kt = tap / 9, r9 = tap - kt * 9, kh = r9 / 3, kw = r9 - kh * 3;
        const int it = t + kt - 1;
        const int ih = 2 * bh_ + kh - 1, iw = 2 * bw_ + kw - 1;
        const bool ok = ((unsigned)it < 64u) && ((unsigned)ih < 32u) && ((unsigned)iw < 32u);
#pragma unroll
        for (int j = 0; j < 4; ++j) { rBh[j] = z4; rBl[j] = z4; }
        if (ok) {
            const size_t src = (((size_t)it * 32 + ih) * 32 + iw) * 256 + ci0 + bsel * 8;
#pragma unroll
            for (int j = 0; j < 4; ++j) {
                rBh[j] = *(const uint4*)(xh + src + j * 8);
                rBl[j] = *(const uint4*)(xl + src + j * 8);
            }
        }
    };

    int tap = 0, ci0 = 0;
    prefetch(0, 0);
    for (int i = 0; i < 108; ++i) {
        __syncthreads();                 // readers of previous tile done
#pragma unroll
        for (int k = 0; k < 4; ++k) {
            *(uint4*)&Ah[asl[k]] = rAh[k];
            *(uint4*)&Al[asl[k]] = rAl[k];
        }
#pragma unroll
        for (int j = 0; j < 4; ++j) {
            *(uint4*)&Bh[bslot[j]] = rBh[j];
            *(uint4*)&Bl[bslot[j]] = rBl[j];
        }
        __syncthreads();                 // tile visible
        int ntap = tap + 1, nci0 = ci0;
        if (ntap == 27) { ntap = 0; nci0 += 64; }
        if (i + 1 < 108) prefetch(ntap, nci0);   // loads fly under MFMA phase
#pragma unroll
        for (int u = 0; u < 2; ++u) {
            const int cs = (u == 0) ? cs0 : cs1;
            half8 ah[4], alo[4], bh8[4], blo[4];
#pragma unroll
            for (int mi = 0; mi < 4; ++mi) {
                ah[mi]  = *(const half8*)&Ah[(wm * 64 + mi * 16 + ml) * 64 + cs];
                alo[mi] = *(const half8*)&Al[(wm * 64 + mi * 16 + ml) * 64 + cs];
            }
#pragma unroll
            for (int ni = 0; ni < 4; ++ni) {
                bh8[ni] = *(const half8*)&Bh[(wn * 64 + ni * 16 + ml) * 64 + cs];
                blo[ni] = *(const half8*)&Bl[(wn * 64 + ni * 16 + ml) * 64 + cs];
            }
#pragma unroll
            for (int mi = 0; mi < 4; ++mi)
#pragma unroll
                for (int ni = 0; ni < 4; ++ni) {
                    acc[mi][ni] = __builtin_amdgcn_mfma_f32_16x16x32_f16(ah[mi],  bh8[ni], acc[mi][ni], 0, 0, 0);
                    acc[mi][ni] = __builtin_amdgcn_mfma_f32_16x16x32_f16(ah[mi],  blo[ni], acc[mi][ni], 0, 0, 0);
                    acc[mi][ni] = __builtin_amdgcn_mfma_f32_16x16x32_f16(alo[mi], bh8[ni], acc[mi][ni], 0, 0, 0);
                }
        }
        tap = ntap; ci0 = nci0;
    }

    // epilogue: unscale, +bias, split fp32 into f16 hi/lo, store channel-last
    const int qr = ql * 4;
#pragma unroll
    for (int mi = 0; mi < 4; ++mi) {
        const int co = co_blk * 128 + wm * 64 + mi * 16 + qr;
#pragma unroll
        for (int ni = 0; ni < 4; ++ni) {
            const int n = wn * 64 + ni * 16 + ml;
            const int h = h0 + (n >> 4), w = n & 15;
            const size_t base = (((size_t)t * 16 + h) * 16 + w) * 512 + co;
            half4 hv, lv;
#pragma unroll
            for (int r = 0; r < 4; ++r) {
                const float v = acc[mi][ni][r] * 0.015625f + b1[co + r];
                const _Float16 hb = (_Float16)v;
                hv[r] = hb;
                lv[r] = (_Float16)(v - (float)hb);
            }
            *(half4*)(yh + base) = hv;
            *(half4*)(yl + base) = lv;
        }
    }
}

// ------------- conv2: pipelined, M=512, N=128 (2t x 8x8), K64/iter, K-split 4 -------------
__global__ __launch_bounds__(256, 2) void conv2_mfma(
        const _Float16* __restrict__ xh, const _Float16* __restrict__ xl,
        const _Float16* __restrict__ wh, const _Float16* __restrict__ wl,
        float* __restrict__ x2p) {
    __shared__ __align__(16) _Float16 Ah[128 * 64];
    __shared__ __align__(16) _Float16 Al[128 * 64];
    __shared__ __align__(16) _Float16 Bh[128 * 64];
    __shared__ __align__(16) _Float16 Bl[128 * 64];
    const int tid = threadIdx.x;
    const int co_blk = blockIdx.x;      // 0..3
    const int tp = blockIdx.y;          // 0..31
    const int ks = blockIdx.z;          // 0..3
    const int wid = tid >> 6, lane = tid & 63;
    const int wm = wid & 1, wn = wid >> 1;
    const int ml = lane & 15, ql = lane >> 4;
    const int cs0 = (ql ^ (ml & 7)) * 8;
    const int cs1 = ((4 + ql) ^ (ml & 7)) * 8;
    int asl[4]; size_t agof[4];
#pragma unroll
    for (int k = 0; k < 4; ++k) {
        const int s = tid + k * 256;
        const int r = s >> 3, c = s & 7;
        asl[k] = r * 64 + (c ^ (r & 7)) * 8;
        agof[k] = (size_t)r * 13824 + c * 8;
    }
    const int brow = tid >> 1, bsel = (tid & 1) * 4, br7 = brow & 7;
    const int btl = brow >> 6, bsp = brow & 63;
    const int bh_ = bsp >> 3, bw_ = bsp & 7;
    int bslot[4];
#pragma unroll
    for (int j = 0; j < 4; ++j) bslot[j] = brow * 64 + ((bsel + j) ^ br7) * 8;

    floatx4 zz = {0.f, 0.f, 0.f, 0.f};
    floatx4 acc[4][4];
#pragma unroll
    for (int i = 0; i < 4; ++i)
#pragma unroll
        for (int j = 0; j < 4; ++j) acc[i][j] = zz;

    const size_t wbo = (size_t)co_blk * 128 * 13824;
    const uint4 z4 = make_uint4(0u, 0u, 0u, 0u);
    uint4 rAh[4], rAl[4], rBh[4], rBl[4];

    auto prefetch = [&](int tap, int ci0) {
        const size_t ab = wbo + (size_t)tap * 512 + ci0;
#pragma unroll
        for (int k = 0; k < 4; ++k) {
            rAh[k] = *(const uint4*)(wh + ab + agof[k]);
            rAl[k] = *(const uint4*)(wl + ab + agof[k]);
        }
        const int kt = tap / 9, r9 = tap - kt * 9, kh = r9 / 3, kw = r9 - kh * 3;
        const int it = tp * 2 + btl + kt - 1;
        const int ih = 2 * bh_ + kh - 1, iw = 2 * bw_ + kw - 1;
        const bool ok = ((unsigned)it < 64u) && ((unsigned)ih < 16u) && ((unsigned)iw < 16u);
#pragma unroll
        for (int j = 0; j < 4; ++j) { rBh[j] = z4; rBl[j] = z4; }
        if (ok) {
            const size_t src = (((size_t)it * 16 + ih) * 16 + iw) * 512 + ci0 + bsel * 8;
#pragma unroll
            for (int j = 0; j < 4; ++j) {
                rBh[j] = *(const uint4*)(xh + src + j * 8);
                rBl[j] = *(const uint4*)(xl + src + j * 8);
            }
        }
    };

    int tap = 0, ci0 = ks * 128;
    prefetch(tap, ci0);
    for (int i = 0; i < 54; ++i) {
        __syncthreads();
#pragma unroll
        for (int k = 0; k < 4; ++k) {
            *(uint4*)&Ah[asl[k]] = rAh[k];
            *(uint4*)&Al[asl[k]] = rAl[k];
        }
#pragma unroll
        for (int j = 0; j < 4; ++j) {
            *(uint4*)&Bh[bslot[j]] = rBh[j];
            *(uint4*)&Bl[bslot[j]] = rBl[j];
        }
        __syncthreads();
        int ntap = tap + 1, nci0 = ci0;
        if (ntap == 27) { ntap = 0; nci0 += 64; }
        if (i + 1 < 54) prefetch(ntap, nci0);
#pragma unroll
        for (int u = 0; u < 2; ++u) {
            const int cs = (u == 0) ? cs0 : cs1;
            half8 ah[4], alo[4], bh8[4], blo[4];
#pragma unroll
            for (int mi = 0; mi < 4; ++mi) {
                ah[mi]  = *(const half8*)&Ah[(wm * 64 + mi * 16 + ml) * 64 + cs];
                alo[mi] = *(const half8*)&Al[(wm * 64 + mi * 16 + ml) * 64 + cs];
            }
#pragma unroll
            for (int ni = 0; ni < 4; ++ni) {
                bh8[ni] = *(const half8*)&Bh[(wn * 64 + ni * 16 + ml) * 64 + cs];
                blo[ni] = *(const half8*)&Bl[(wn * 64 + ni * 16 + ml) * 64 + cs];
            }
#pragma unroll
            for (int mi = 0; mi < 4; ++mi)
#pragma unroll
                for (int ni = 0; ni < 4; ++ni) {
                    acc[mi][ni] = __builtin_amdgcn_mfma_f32_16x16x32_f16(ah[mi],  bh8[ni], acc[mi][ni], 0, 0, 0);
                    acc[mi][ni] = __builtin_amdgcn_mfma_f32_16x16x32_f16(ah[mi],  blo[ni], acc[mi][ni], 0, 0, 0);
                    acc[mi][ni] = __builtin_amdgcn_mfma_f32_16x16x32_f16(alo[mi], bh8[ni], acc[mi][ni], 0, 0, 0);
                }
        }
        tap = ntap; ci0 = nci0;
    }

    const int qr = ql * 4;
#pragma unroll
    for (int mi = 0; mi < 4; ++mi) {
        const int co = co_blk * 128 + wm * 64 + mi * 16 + qr;
#pragma unroll
        for (int ni = 0; ni < 4; ++ni) {
            const int n = wn * 64 + ni * 16 + ml;
            const int ng = tp * 128 + n;
            float4 v;
            v.x = acc[mi][ni][0]; v.y = acc[mi][ni][1];
            v.z = acc[mi][ni][2]; v.w = acc[mi][ni][3];
            *(float4*)&x2p[((size_t)ks * 4096 + ng) * 512 + co] = v;
        }
    }
}

// ------------- fused feat (K-split sum + spatial max + bias) and head matvec -------------
__global__ __launch_bounds__(256) void feat_head(
        const float* __restrict__ x2p, const float* __restrict__ b2,
        const float* __restrict__ sw, const float* __restrict__ sb,
        const float* __restrict__ dw, const float* __restrict__ db,
        float* __restrict__ scoreL, float* __restrict__ deltaL) {
    __shared__ float fr[512];
    __shared__ float partial[32][8];
    const int t = blockIdx.x, tid = threadIdx.x;
#pragma unroll
    for (int cc = 0; cc < 2; ++cc) {
        const int c = tid + cc * 256;
        float mx = -3.4e38f;
        for (int sp = 0; sp < 64; ++sp) {
            const size_t ng = (size_t)t * 64 + sp;
            const float s = x2p[ng * 512 + c]
                          + x2p[((size_t)4096 + ng) * 512 + c]
                          + x2p[((size_t)8192 + ng) * 512 + c]
                          + x2p[((size_t)12288 + ng) * 512 + c];
            mx = fmaxf(mx, s);
        }
        fr[c] = mx * 0.015625f + b2[c];
    }
    __syncthreads();
    const int o = tid & 31, part = tid >> 5;
    const float* wrow = (o < 16) ? (sw + (size_t)o * 512) : (dw + (size_t)(o - 16) * 512);
    float s = 0.f;
    const int j0 = part * 64;
#pragma unroll 16
    for (int j = 0; j < 64; ++j) s += wrow[j0 + j] * fr[j0 + j];
    partial[o][part] = s;
    __syncthreads();
    if (tid < 32) {
        float tot = 0.f;
#pragma unroll
        for (int p = 0; p < 8; ++p) tot += partial[tid][p];
        tot += (tid < 16) ? sb[tid] : db[tid - 16];
        if (tid < 16) scoreL[tid * 64 + t] = tot;
        else deltaL[(tid - 16) * 64 + t] = tot;
    }
}

// ------------- NMS + labels + losses: SINGLE WAVE (64 lanes), no barriers -------------
__global__ void nms_loss_kernel(const float* __restrict__ scoreL,
                                const float* __restrict__ deltaL,
                                const float* __restrict__ gt,
                                const int* __restrict__ video_len,
                                float* __restrict__ out) {
    const int lane = threadIdx.x & 63;
    float gsv[8], gev[8];
#pragma unroll
    for (int g = 0; g < 8; ++g) { gsv[g] = gt[2 * g]; gev[g] = gt[2 * g + 1]; }
    const float center = ((float)lane + 0.5f) * 8.0f;
    float psv[8], pev[8], fg[8], l0v[8], l1v[8], dcv[8], dlv[8];
#pragma unroll
    for (int j = 0; j < 8; ++j) {
        const float s0 = scoreL[j * 64 + lane], s1 = scoreL[(8 + j) * 64 + lane];
        const float mm = fmaxf(s0, s1);
        const float lse = mm + logf(expf(s0 - mm) + expf(s1 - mm));
        l0v[j] = s0 - lse; l1v[j] = s1 - lse;
        const float dc = deltaL[j * 64 + lane], dl = deltaL[(8 + j) * 64 + lane];
        dcv[j] = dc; dlv[j] = dl;
        const float alen = 8.0f * (float)(1 << j);
        const float pc = center + dc * alen;
        const float pl = alen * expf(fminf(fmaxf(dl, -10.0f), 10.0f));
        const float ps = fminf(fmaxf(pc - pl * 0.5f, 0.0f), 512.0f);
        const float pe = fminf(fmaxf(pc + pl * 0.5f, 0.0f), 512.0f);
        psv[j] = ps; pev[j] = pe;
        fg[j] = ((pe - ps) >= 4.0f) ? expf(l1v[j]) : -1e9f;
    }
    for (int itn = 0; itn < 100; ++itn) {
        float v = fg[0]; int idx = lane;
#pragma unroll
        for (int j = 1; j < 8; ++j) if (fg[j] > v) { v = fg[j]; idx = lane + 64 * j; }
#pragma unroll
        for (int off = 32; off > 0; off >>= 1) {
            const float ov = __shfl_down(v, off);
            const int oi = __shfl_down(idx, off);
            if (ov > v || (ov == v && oi < idx)) { v = ov; idx = oi; }
        }
        v = __shfl(v, 0); idx = __shfl(idx, 0);
        const int wj = idx >> 6, wl = idx & 63;
        float bw0 = 0.f, bw1 = 0.f;
#pragma unroll
        for (int j = 0; j < 8; ++j) if (j == wj) { bw0 = psv[j]; bw1 = pev[j]; }
        const float b0 = __shfl(bw0, wl);
        const float b1 = __shfl(bw1, wl);
        if (lane == 0) {
            const bool kept = v > -5e8f;
            out[2 * itn] = kept ? b0 : 0.0f;
            out[2 * itn + 1] = kept ? b1 : 0.0f;
            out[200 + itn] = kept ? v : 0.0f;
        }
#pragma unroll
        for (int j = 0; j < 8; ++j) {
            const int n = lane + 64 * j;
            const float inter = fmaxf(fminf(b1, pev[j]) - fmaxf(b0, psv[j]), 0.0f);
            const float uni = (b1 - b0) + (pev[j] - psv[j]) - inter;
            const float iou = inter / fmaxf(uni, 1e-6f);
            if (iou > 0.7f || n == idx) fg[j] = -1e9f;
        }
    }
    int labv[8], aggv[8];
#pragma unroll
    for (int j = 0; j < 8; ++j) {
        const float alen = 8.0f * (float)(1 << j);
        const float as_ = center - alen * 0.5f, ae_ = center + alen * 0.5f;
        float mx = -1.0f; int ag = 0;
#pragma unroll
        for (int g = 0; g < 8; ++g) {
            const float inter = fmaxf(fminf(ae_, gev[g]) - fmaxf(as_, gsv[g]), 0.0f);
            const float uni = (ae_ - as_) + (gev[g] - gsv[g]) - inter;
            const float iou = inter / fmaxf(uni, 1e-6f);
            if (iou > mx) { mx = iou; ag = g; }
        }
        labv[j] = (mx < 0.3f) ? 0 : ((mx >= 0.7f) ? 1 : -1);
        aggv[j] = ag;
    }
    for (int g = 0; g < 8; ++g) {
        float v = -1.0f; int idx = 0;
#pragma unroll
        for (int j = 0; j < 8; ++j) {
            const int n = lane + 64 * j;
            const float alen = 8.0f * (float)(1 << j);
            const float as_ = center - alen * 0.5f, ae_ = center + alen * 0.5f;
            const float inter = fmaxf(fminf(ae_, gev[g]) - fmaxf(as_, gsv[g]), 0.0f);
            const float uni = (ae_ - as_) + (gev[g] - gsv[g]) - inter;
            const float iou = inter / fmaxf(uni, 1e-6f);
            if (iou > v || (iou == v && n < idx)) { v = iou; idx = n; }
        }
#pragma unroll
        for (int off = 32; off > 0; off >>= 1) {
            const float ov = __shfl_down(v, off);
            const int oi = __shfl_down(idx, off);
            if (ov > v || (ov == v && oi < idx)) { v = ov; idx = oi; }
        }
        idx = __shfl(idx, 0);
#pragma unroll
        for (int j = 0; j < 8; ++j)
            if (lane == (idx & 63) && j == (idx >> 6)) labv[j] = 1;
    }
    const float vl = (float)video_len[0];
    float nll_s = 0.f, msk_s = 0.f, reg_s = 0.f, pos_s = 0.f;
#pragma unroll
    for (int j = 0; j < 8; ++j) {
        const float alen = 8.0f * (float)(1 << j);
        const float as_ = center - alen * 0.5f, ae_ = center + alen * 0.5f;
        int l = labv[j];
        if (!((as_ >= 0.0f) && (ae_ <= vl))) l = -1;
        if (l >= 0) {
            msk_s += 1.0f;
            nll_s -= (l == 1) ? l1v[j] : l0v[j];
            if (l == 1) {
                pos_s += 1.0f;
                float gcv = 0.f, glv = 0.f;
#pragma unroll
                for (int g = 0; g < 8; ++g)
                    if (g == aggv[j]) {
                        gcv = (gsv[g] + gev[g]) * 0.5f;
                        glv = fmaxf(gev[g] - gsv[g], 1e-6f);
                    }
                const float r0 = (gcv - center) / alen;
                const float r1 = logf(glv / alen);
                const float d0 = dcv[j] - r0, d1 = dlv[j] - r1;
                float s = (fabsf(d0) < 1.0f) ? (0.5f * d0 * d0) : (fabsf(d0) - 0.5f);
                s += (fabsf(d1) < 1.0f) ? (0.5f * d1 * d1) : (fabsf(d1) - 0.5f);
                reg_s += s;
            }
        }
    }
    float sums[4] = {nll_s, msk_s, reg_s, pos_s};
#pragma unroll
    for (int k = 0; k < 4; ++k)
#pragma unroll
        for (int off = 32; off > 0; off >>= 1) sums[k] += __shfl_down(sums[k], off);
    if (lane == 0) {
        out[300] = sums[0] / fmaxf(sums[1], 1.0f);
        out[301] = sums[2] / fmaxf(sums[3], 1.0f);
    }
}

extern "C" void kernel_launch(void* const* d_in, const int* in_sizes, int n_in,
                              void* d_out, int out_size, void* d_ws, size_t ws_size,
                              hipStream_t stream) {
    const float* base_feat = (const float*)d_in[0];
    const float* gt        = (const float*)d_in[1];
    const int*   video_len = (const int*)d_in[2];
    const float* w1        = (const float*)d_in[3];
    const float* b1        = (const float*)d_in[4];
    const float* w2        = (const float*)d_in[5];
    const float* b2        = (const float*)d_in[6];
    const float* sw        = (const float*)d_in[7];
    const float* sb        = (const float*)d_in[8];
    const float* dw        = (const float*)d_in[9];
    const float* db        = (const float*)d_in[10];

    char* ws = (char*)d_ws;
    _Float16* w1h = (_Float16*)ws;  ws += (size_t)512 * 6912 * 2;
    _Float16* w1l = (_Float16*)ws;  ws += (size_t)512 * 6912 * 2;
    _Float16* w2h = (_Float16*)ws;  ws += (size_t)512 * 13824 * 2;
    _Float16* w2l = (_Float16*)ws;  ws += (size_t)512 * 13824 * 2;
    _Float16* inh = (_Float16*)ws;  ws += (size_t)65536 * 256 * 2;
    _Float16* inl = (_Float16*)ws;  ws += (size_t)65536 * 256 * 2;
    _Float16* x1h = (_Float16*)ws;  ws += (size_t)64 * 16 * 16 * 512 * 2;
    _Float16* x1l = (_Float16*)ws;  ws += (size_t)64 * 16 * 16 * 512 * 2;
    float* scoreL = (float*)ws;     ws += (size_t)16 * 64 * 4;
    float* deltaL = (float*)ws;     ws += (size_t)16 * 64 * 4;
    // x2p (4, 4096, 512) fp32 = 33.5 MB reuses the inh region (consumed by conv1)
    float* x2p = (float*)inh;

    wt_split_t<<<1024, 256, 0, stream>>>(w1, w1h, w1l, w2, w2h, w2l);
    in_split<<<dim3(2, 1024), 256, 0, stream>>>(base_feat, inh, inl);
    conv1_mfma<<<dim3(4, 64, 2), 256, 0, stream>>>(inh, inl, w1h, w1l, b1, x1h, x1l);
    conv2_mfma<<<dim3(4, 32, 4), 256, 0, stream>>>(x1h, x1l, w2h, w2l, x2p);
    feat_head<<<64, 256, 0, stream>>>(x2p, b2, sw, sb, dw, db, scoreL, deltaL);
    nms_loss_kernel<<<1, 64, 0, stream>>>(scoreL, deltaL, gt, video_len,
                                          (float*)d_out);
}

// Round 6
// 971.119 us; speedup vs baseline: 1.0358x; 1.0358x over previous
//
#include <hip/hip_runtime.h>

typedef __attribute__((ext_vector_type(8))) _Float16 half8;
typedef __attribute__((ext_vector_type(4))) _Float16 half4;
typedef __attribute__((ext_vector_type(4))) float floatx4;

#define DI __device__ __forceinline__

DI void gl_lds16(const void* g, void* l) {
    __builtin_amdgcn_global_load_lds(
        (__attribute__((address_space(1))) void*)(g),
        (__attribute__((address_space(3))) void*)(l), 16, 0, 0);
}

// ------------- weight split via LDS transpose + zero-page init -------------
__global__ __launch_bounds__(256) void wt_split_t(
        const float* __restrict__ w1, _Float16* __restrict__ w1h, _Float16* __restrict__ w1l,
        const float* __restrict__ w2, _Float16* __restrict__ w2h, _Float16* __restrict__ w2l,
        float* __restrict__ zp) {
    __shared__ float L[13824];
    const int b = blockIdx.x;
    const int tid = threadIdx.x;
    if (b == 0 && tid < 64) zp[tid] = 0.0f;      // 256B zero page for conv DMA OOB
    if (b < 512) {
        const float* src = w1 + (size_t)b * 6912;
        for (int idx = tid; idx < 6912; idx += 256) L[idx] = src[idx] * 64.0f;
        __syncthreads();
        for (int c = tid; c < 864; c += 256) {
            const int tap = c >> 5, ci0 = (c & 31) * 8;
            half8 h, l;
#pragma unroll
            for (int j = 0; j < 8; ++j) {
                const float x = L[(ci0 + j) * 27 + tap];
                const _Float16 hh = (_Float16)x;
                h[j] = hh; l[j] = (_Float16)(x - (float)hh);
            }
            const size_t off = (size_t)b * 6912 + tap * 256 + ci0;
            *(half8*)&w1h[off] = h;
            *(half8*)&w1l[off] = l;
        }
    } else {
        const float* src = w2 + (size_t)(b - 512) * 13824;
        for (int idx = tid; idx < 13824; idx += 256) L[idx] = src[idx] * 64.0f;
        __syncthreads();
        for (int c = tid; c < 1728; c += 256) {
            const int tap = c >> 6, ci0 = (c & 63) * 8;
            half8 h, l;
#pragma unroll
            for (int j = 0; j < 8; ++j) {
                const float x = L[(ci0 + j) * 27 + tap];
                const _Float16 hh = (_Float16)x;
                h[j] = hh; l[j] = (_Float16)(x - (float)hh);
            }
            const size_t off = (size_t)(b - 512) * 13824 + tap * 512 + ci0;
            *(half8*)&w2h[off] = h;
            *(half8*)&w2l[off] = l;
        }
    }
}

// ------------- input split via LDS transpose: (256,65536) fp32 -> (65536,256) f16 hi/lo -------------
__global__ __launch_bounds__(256) void in_split(const float* __restrict__ in,
                                                _Float16* __restrict__ oh,
                                                _Float16* __restrict__ ol) {
    __shared__ float T[128 * 65];
    const int hb = blockIdx.x;
    const int s0 = blockIdx.y * 64;
    const int tid = threadIdx.x;
    const int cil = tid >> 1, part = tid & 1;
    const float* src = in + (size_t)(hb * 128 + cil) * 65536 + s0 + part * 32;
    float v[32];
#pragma unroll
    for (int q = 0; q < 8; ++q) *(float4*)(v + q * 4) = *(const float4*)(src + q * 4);
#pragma unroll
    for (int j = 0; j < 32; ++j) T[cil * 65 + part * 32 + j] = v[j];
    __syncthreads();
#pragma unroll
    for (int k = 0; k < 4; ++k) {
        const int c = tid + k * 256;
        const int sp = c >> 4, o = c & 15, ci0 = o * 8;
        half8 h, l;
#pragma unroll
        for (int j = 0; j < 8; ++j) {
            const float x = T[(ci0 + j) * 65 + sp];
            const _Float16 hh = (_Float16)x;
            h[j] = hh; l[j] = (_Float16)(x - (float)hh);
        }
        const size_t off = (size_t)(s0 + sp) * 256 + hb * 128 + ci0;
        *(half8*)&oh[off] = h;
        *(half8*)&ol[off] = l;
    }
}

// ---------- conv1: LDS double-buffered DMA pipeline, K32/iter (hi|lo combined rows) ----------
// A row layout (128B): halfs[0..31]=hi k, halfs[32..63]=lo k; chunk swizzle p = c ^ (row&7)
__global__ __launch_bounds__(256, 2) void conv1_mfma(
        const _Float16* __restrict__ xh, const _Float16* __restrict__ xl,
        const _Float16* __restrict__ wh, const _Float16* __restrict__ wl,
        const float* __restrict__ b1, const _Float16* __restrict__ zp,
        _Float16* __restrict__ yh, _Float16* __restrict__ yl) {
    __shared__ __align__(16) _Float16 A2[2][128 * 64];
    __shared__ __align__(16) _Float16 B2[2][128 * 64];
    const int tid = threadIdx.x;
    const int co_blk = blockIdx.x;      // 0..3
    const int t = blockIdx.y;           // 0..63
    const int h0 = blockIdx.z * 8;      // 0 or 8
    const int wid = tid >> 6, lane = tid & 63;
    const int wm = wid & 1, wn = wid >> 1;
    const int ml = lane & 15, ql = lane >> 4;
    const int cs0 = (ql ^ (ml & 7)) * 8;          // hi chunk ql
    const int cs1 = ((4 + ql) ^ (ml & 7)) * 8;    // lo chunk ql
    // staging lane constants
    const int sl = lane & 7, rl = lane >> 3;
    const int lc = sl ^ rl;                        // logical chunk 0..7
    const int koff = (lc & 3) * 8;                 // k-octet within 32-half row
    const _Float16* wsrc = (lc < 4) ? wh : wl;
    const _Float16* xsrc = (lc < 4) ? xh : xl;
    size_t aoffq[4]; int dstq[4], ih2[4], iw2[4];
    const size_t wbo = (size_t)co_blk * 128 * 6912;
#pragma unroll
    for (int q = 0; q < 4; ++q) {
        const int row = (q * 4 + wid) * 8 + rl;    // A: co row / B: n row
        aoffq[q] = wbo + (size_t)row * 6912 + koff;
        dstq[q] = (q * 4 + wid) * 512 + lane * 8;
        const int h = h0 + (row >> 4), w = row & 15;
        ih2[q] = 2 * h - 1; iw2[q] = 2 * w - 1;
    }

    floatx4 zz = {0.f, 0.f, 0.f, 0.f};
    floatx4 acc[4][4];
#pragma unroll
    for (int i = 0; i < 4; ++i)
#pragma unroll
        for (int j = 0; j < 4; ++j) acc[i][j] = zz;

    auto stage = [&](int kt, int kh, int kw, int ci0, int bi) {
        const int tap = (kt * 3 + kh) * 3 + kw;
        const size_t ab = (size_t)tap * 256 + ci0;
        _Float16* Ad = A2[bi]; _Float16* Bd = B2[bi];
        const int it = t + kt - 1;
        const bool tok = ((unsigned)it < 64u);
        const size_t tbase = ((size_t)it * 1024) * 256 + ci0 + koff;
#pragma unroll
        for (int q = 0; q < 4; ++q) {
            gl_lds16(wsrc + aoffq[q] + ab, &Ad[dstq[q]]);
            const int ih = ih2[q] + kh, iw = iw2[q] + kw;
            const bool ok = tok && ((unsigned)ih < 32u) && ((unsigned)iw < 32u);
            const _Float16* src = ok ? (xsrc + tbase + ((size_t)ih * 32 + iw) * 256)
                                     : (zp + koff);
            gl_lds16(src, &Bd[dstq[q]]);
        }
    };

    int kt = 0, kh = 0, kw = 0, ci0 = 0;
    stage(0, 0, 0, 0, 0);
    kw = 1;
    for (int i = 0; i < 216; ++i) {
        __syncthreads();      // drains DMA for buf (issued last iter, flew under MFMA)
        if (i + 1 < 216) {
            stage(kt, kh, kw, ci0, (i + 1) & 1);
            if (++kw == 3) { kw = 0; if (++kh == 3) { kh = 0; if (++kt == 3) { kt = 0; ci0 += 32; } } }
        }
        const _Float16* Ab = A2[i & 1];
        const _Float16* Bb = B2[i & 1];
        half8 ah[4], alo[4], bh8[4], blo[4];
#pragma unroll
        for (int mi = 0; mi < 4; ++mi) {
            ah[mi]  = *(const half8*)&Ab[(wm * 64 + mi * 16 + ml) * 64 + cs0];
            alo[mi] = *(const half8*)&Ab[(wm * 64 + mi * 16 + ml) * 64 + cs1];
        }
#pragma unroll
        for (int ni = 0; ni < 4; ++ni) {
            bh8[ni] = *(const half8*)&Bb[(wn * 64 + ni * 16 + ml) * 64 + cs0];
            blo[ni] = *(const half8*)&Bb[(wn * 64 + ni * 16 + ml) * 64 + cs1];
        }
#pragma unroll
        for (int mi = 0; mi < 4; ++mi)
#pragma unroll
            for (int ni = 0; ni < 4; ++ni) {
                acc[mi][ni] = __builtin_amdgcn_mfma_f32_16x16x32_f16(ah[mi],  bh8[ni], acc[mi][ni], 0, 0, 0);
                acc[mi][ni] = __builtin_amdgcn_mfma_f32_16x16x32_f16(ah[mi],  blo[ni], acc[mi][ni], 0, 0, 0);
                acc[mi][ni] = __builtin_amdgcn_mfma_f32_16x16x32_f16(alo[mi], bh8[ni], acc[mi][ni], 0, 0, 0);
            }
    }

    const int qr = ql * 4;
#pragma unroll
    for (int mi = 0; mi < 4; ++mi) {
        const int co = co_blk * 128 + wm * 64 + mi * 16 + qr;
#pragma unroll
        for (int ni = 0; ni < 4; ++ni) {
            const int n = wn * 64 + ni * 16 + ml;
            const int h = h0 + (n >> 4), w = n & 15;
            const size_t base = (((size_t)t * 16 + h) * 16 + w) * 512 + co;
            half4 hv, lv;
#pragma unroll
            for (int r = 0; r < 4; ++r) {
                const float v = acc[mi][ni][r] * 0.015625f + b1[co + r];
                const _Float16 hb = (_Float16)v;
                hv[r] = hb;
                lv[r] = (_Float16)(v - (float)hb);
            }
            *(half4*)(yh + base) = hv;
            *(half4*)(yl + base) = lv;
        }
    }
}

// ---------- conv2: same dbuf pipeline, N=128 (2t x 8x8), K-split 4, 108 iters ----------
__global__ __launch_bounds__(256, 2) void conv2_mfma(
        const _Float16* __restrict__ xh, const _Float16* __restrict__ xl,
        const _Float16* __restrict__ wh, const _Float16* __restrict__ wl,
        const _Float16* __restrict__ zp,
        float* __restrict__ x2p) {
    __shared__ __align__(16) _Float16 A2[2][128 * 64];
    __shared__ __align__(16) _Float16 B2[2][128 * 64];
    const int tid = threadIdx.x;
    const int co_blk = blockIdx.x;      // 0..3
    const int tp = blockIdx.y;          // 0..31
    const int ks = blockIdx.z;          // 0..3
    const int wid = tid >> 6, lane = tid & 63;
    const int wm = wid & 1, wn = wid >> 1;
    const int ml = lane & 15, ql = lane >> 4;
    const int cs0 = (ql ^ (ml & 7)) * 8;
    const int cs1 = ((4 + ql) ^ (ml & 7)) * 8;
    const int sl = lane & 7, rl = lane >> 3;
    const int lc = sl ^ rl;
    const int koff = (lc & 3) * 8;
    const _Float16* wsrc = (lc < 4) ? wh : wl;
    const _Float16* xsrc = (lc < 4) ? xh : xl;
    size_t aoffq[4]; int dstq[4], ih2[4], iw2[4], tl4[4];
    const size_t wbo = (size_t)co_blk * 128 * 13824;
#pragma unroll
    for (int q = 0; q < 4; ++q) {
        const int row = (q * 4 + wid) * 8 + rl;
        aoffq[q] = wbo + (size_t)row * 13824 + koff;
        dstq[q] = (q * 4 + wid) * 512 + lane * 8;
        const int sp = row & 63;
        tl4[q] = row >> 6;
        ih2[q] = 2 * (sp >> 3) - 1; iw2[q] = 2 * (sp & 7) - 1;
    }

    floatx4 zz = {0.f, 0.f, 0.f, 0.f};
    floatx4 acc[4][4];
#pragma unroll
    for (int i = 0; i < 4; ++i)
#pragma unroll
        for (int j = 0; j < 4; ++j) acc[i][j] = zz;

    auto stage = [&](int kt, int kh, int kw, int ci0, int bi) {
        const int tap = (kt * 3 + kh) * 3 + kw;
        const size_t ab = (size_t)tap * 512 + ci0;
        _Float16* Ad = A2[bi]; _Float16* Bd = B2[bi];
#pragma unroll
        for (int q = 0; q < 4; ++q) {
            gl_lds16(wsrc + aoffq[q] + ab, &Ad[dstq[q]]);
            const int it = tp * 2 + tl4[q] + kt - 1;
            const int ih = ih2[q] + kh, iw = iw2[q] + kw;
            const bool ok = ((unsigned)it < 64u) && ((unsigned)ih < 16u) && ((unsigned)iw < 16u);
            const _Float16* src = ok ? (xsrc + (((size_t)it * 16 + ih) * 16 + iw) * 512 + ci0 + koff)
                                     : (zp + koff);
            gl_lds16(src, &Bd[dstq[q]]);
        }
    };

    int kt = 0, kh = 0, kw = 0, ci0 = ks * 128;
    stage(0, 0, 0, ci0, 0);
    kw = 1;
    for (int i = 0; i < 108; ++i) {
        __syncthreads();
        if (i + 1 < 108) {
            stage(kt, kh, kw, ci0, (i + 1) & 1);
            if (++kw == 3) { kw = 0; if (++kh == 3) { kh = 0; if (++kt == 3) { kt = 0; ci0 += 32; } } }
        }
        const _Float16* Ab = A2[i & 1];
        const _Float16* Bb = B2[i & 1];
        half8 ah[4], alo[4], bh8[4], blo[4];
#pragma unroll
        for (int mi = 0; mi < 4; ++mi) {
            ah[mi]  = *(const half8*)&Ab[(wm * 64 + mi * 16 + ml) * 64 + cs0];
            alo[mi] = *(const half8*)&Ab[(wm * 64 + mi * 16 + ml) * 64 + cs1];
        }
#pragma unroll
        for (int ni = 0; ni < 4; ++ni) {
            bh8[ni] = *(const half8*)&Bb[(wn * 64 + ni * 16 + ml) * 64 + cs0];
            blo[ni] = *(const half8*)&Bb[(wn * 64 + ni * 16 + ml) * 64 + cs1];
        }
#pragma unroll
        for (int mi = 0; mi < 4; ++mi)
#pragma unroll
            for (int ni = 0; ni < 4; ++ni) {
                acc[mi][ni] = __builtin_amdgcn_mfma_f32_16x16x32_f16(ah[mi],  bh8[ni], acc[mi][ni], 0, 0, 0);
                acc[mi][ni] = __builtin_amdgcn_mfma_f32_16x16x32_f16(ah[mi],  blo[ni], acc[mi][ni], 0, 0, 0);
                acc[mi][ni] = __builtin_amdgcn_mfma_f32_16x16x32_f16(alo[mi], bh8[ni], acc[mi][ni], 0, 0, 0);
            }
    }

    const int qr = ql * 4;
#pragma unroll
    for (int mi = 0; mi < 4; ++mi) {
        const int co = co_blk * 128 + wm * 64 + mi * 16 + qr;
#pragma unroll
        for (int ni = 0; ni < 4; ++ni) {
            const int n = wn * 64 + ni * 16 + ml;
            const int ng = tp * 128 + n;
            float4 v;
            v.x = acc[mi][ni][0]; v.y = acc[mi][ni][1];
            v.z = acc[mi][ni][2]; v.w = acc[mi][ni][3];
            *(float4*)&x2p[((size_t)ks * 4096 + ng) * 512 + co] = v;
        }
    }
}

// ------------- fused feat (K-split sum + spatial max + bias) and head matvec -------------
__global__ __launch_bounds__(256) void feat_head(
        const float* __restrict__ x2p, const float* __restrict__ b2,
        const float* __restrict__ sw, const float* __restrict__ sb,
        const float* __restrict__ dw, const float* __restrict__ db,
        float* __restrict__ scoreL, float* __restrict__ deltaL) {
    __shared__ float fr[512];
    __shared__ float partial[32][8];
    const int t = blockIdx.x, tid = threadIdx.x;
#pragma unroll
    for (int cc = 0; cc < 2; ++cc) {
        const int c = tid + cc * 256;
        float mx = -3.4e38f;
        for (int sp = 0; sp < 64; ++sp) {
            const size_t ng = (size_t)t * 64 + sp;
            const float s = x2p[ng * 512 + c]
                          + x2p[((size_t)4096 + ng) * 512 + c]
                          + x2p[((size_t)8192 + ng) * 512 + c]
                          + x2p[((size_t)12288 + ng) * 512 + c];
            mx = fmaxf(mx, s);
        }
        fr[c] = mx * 0.015625f + b2[c];
    }
    __syncthreads();
    const int o = tid & 31, part = tid >> 5;
    const float* wrow = (o < 16) ? (sw + (size_t)o * 512) : (dw + (size_t)(o - 16) * 512);
    float s = 0.f;
    const int j0 = part * 64;
#pragma unroll 16
    for (int j = 0; j < 64; ++j) s += wrow[j0 + j] * fr[j0 + j];
    partial[o][part] = s;
    __syncthreads();
    if (tid < 32) {
        float tot = 0.f;
#pragma unroll
        for (int p = 0; p < 8; ++p) tot += partial[tid][p];
        tot += (tid < 16) ? sb[tid] : db[tid - 16];
        if (tid < 16) scoreL[tid * 64 + t] = tot;
        else deltaL[(tid - 16) * 64 + t] = tot;
    }
}

// ------------- NMS + labels + losses: SINGLE WAVE (64 lanes), no barriers -------------
__global__ void nms_loss_kernel(const float* __restrict__ scoreL,
                                const float* __restrict__ deltaL,
                                const float* __restrict__ gt,
                                const int* __restrict__ video_len,
                                float* __restrict__ out) {
    const int lane = threadIdx.x & 63;
    float gsv[8], gev[8];
#pragma unroll
    for (int g = 0; g < 8; ++g) { gsv[g] = gt[2 * g]; gev[g] = gt[2 * g + 1]; }
    const float center = ((float)lane + 0.5f) * 8.0f;
    float psv[8], pev[8], fg[8], l0v[8], l1v[8], dcv[8], dlv[8];
#pragma unroll
    for (int j = 0; j < 8; ++j) {
        const float s0 = scoreL[j * 64 + lane], s1 = scoreL[(8 + j) * 64 + lane];
        const float mm = fmaxf(s0, s1);
        const float lse = mm + logf(expf(s0 - mm) + expf(s1 - mm));
        l0v[j] = s0 - lse; l1v[j] = s1 - lse;
        const float dc = deltaL[j * 64 + lane], dl = deltaL[(8 + j) * 64 + lane];
        dcv[j] = dc; dlv[j] = dl;
        const float alen = 8.0f * (float)(1 << j);
        const float pc = center + dc * alen;
        const float pl = alen * expf(fminf(fmaxf(dl, -10.0f), 10.0f));
        const float ps = fminf(fmaxf(pc - pl * 0.5f, 0.0f), 512.0f);
        const float pe = fminf(fmaxf(pc + pl * 0.5f, 0.0f), 512.0f);
        psv[j] = ps; pev[j] = pe;
        fg[j] = ((pe - ps) >= 4.0f) ? expf(l1v[j]) : -1e9f;
    }
    for (int itn = 0; itn < 100; ++itn) {
        float v = fg[0]; int idx = lane;
#pragma unroll
        for (int j = 1; j < 8; ++j) if (fg[j] > v) { v = fg[j]; idx = lane + 64 * j; }
#pragma unroll
        for (int off = 32; off > 0; off >>= 1) {
            const float ov = __shfl_down(v, off);
            const int oi = __shfl_down(idx, off);
            if (ov > v || (ov == v && oi < idx)) { v = ov; idx = oi; }
        }
        v = __shfl(v, 0); idx = __shfl(idx, 0);
        const int wj = idx >> 6, wl = idx & 63;
        float bw0 = 0.f, bw1 = 0.f;
#pragma unroll
        for (int j = 0; j < 8; ++j) if (j == wj) { bw0 = psv[j]; bw1 = pev[j]; }
        const float b0 = __shfl(bw0, wl);
        const float b1 = __shfl(bw1, wl);
        if (lane == 0) {
            const bool kept = v > -5e8f;
            out[2 * itn] = kept ? b0 : 0.0f;
            out[2 * itn + 1] = kept ? b1 : 0.0f;
            out[200 + itn] = kept ? v : 0.0f;
        }
#pragma unroll
        for (int j = 0; j < 8; ++j) {
            const int n = lane + 64 * j;
            const float inter = fmaxf(fminf(b1, pev[j]) - fmaxf(b0, psv[j]), 0.0f);
            const float uni = (b1 - b0) + (pev[j] - psv[j]) - inter;
            const float iou = inter / fmaxf(uni, 1e-6f);
            if (iou > 0.7f || n == idx) fg[j] = -1e9f;
        }
    }
    int labv[8], aggv[8];
#pragma unroll
    for (int j = 0; j < 8; ++j) {
        const float alen = 8.0f * (float)(1 << j);
        const float as_ = center - alen * 0.5f, ae_ = center + alen * 0.5f;
        float mx = -1.0f; int ag = 0;
#pragma unroll
        for (int g = 0; g < 8; ++g) {
            const float inter = fmaxf(fminf(ae_, gev[g]) - fmaxf(as_, gsv[g]), 0.0f);
            const float uni = (ae_ - as_) + (gev[g] - gsv[g]) - inter;
            const float iou = inter / fmaxf(uni, 1e-6f);
            if (iou > mx) { mx = iou; ag = g; }
        }
        labv[j] = (mx < 0.3f) ? 0 : ((mx >= 0.7f) ? 1 : -1);
        aggv[j] = ag;
    }
    for (int g = 0; g < 8; ++g) {
        float v = -1.0f; int idx = 0;
#pragma unroll
        for (int j = 0; j < 8; ++j) {
            const int n = lane + 64 * j;
            const float alen = 8.0f * (float)(1 << j);
            const float as_ = center - alen * 0.5f, ae_ = center + alen * 0.5f;
            const float inter = fmaxf(fminf(ae_, gev[g]) - fmaxf(as_, gsv[g]), 0.0f);
            const float uni = (ae_ - as_) + (gev[g] - gsv[g]) - inter;
            const float iou = inter / fmaxf(uni, 1e-6f);
            if (iou > v || (iou == v && n < idx)) { v = iou; idx = n; }
        }
#pragma unroll
        for (int off = 32; off > 0; off >>= 1) {
            const float ov = __shfl_down(v, off);
            const int oi = __shfl_down(idx, off);
            if (ov > v || (ov == v && oi < idx)) { v = ov; idx = oi; }
        }
        idx = __shfl(idx, 0);
#pragma unroll
        for (int j = 0; j < 8; ++j)
            if (lane == (idx & 63) && j == (idx >> 6)) labv[j] = 1;
    }
    const float vl = (float)video_len[0];
    float nll_s = 0.f, msk_s = 0.f, reg_s = 0.f, pos_s = 0.f;
#pragma unroll
    for (int j = 0; j < 8; ++j) {
        const float alen = 8.0f * (float)(1 << j);
        const float as_ = center - alen * 0.5f, ae_ = center + alen * 0.5f;
        int l = labv[j];
        if (!((as_ >= 0.0f) && (ae_ <= vl))) l = -1;
        if (l >= 0) {
            msk_s += 1.0f;
            nll_s -= (l == 1) ? l1v[j] : l0v[j];
            if (l == 1) {
                pos_s += 1.0f;
                float gcv = 0.f, glv = 0.f;
#pragma unroll
                for (int g = 0; g < 8; ++g)
                    if (g == aggv[j]) {
                        gcv = (gsv[g] + gev[g]) * 0.5f;
                        glv = fmaxf(gev[g] - gsv[g], 1e-6f);
                    }
                const float r0 = (gcv - center) / alen;
                const float r1 = logf(glv / alen);
                const float d0 = dcv[j] - r0, d1 = dlv[j] - r1;
                float s = (fabsf(d0) < 1.0f) ? (0.5f * d0 * d0) : (fabsf(d0) - 0.5f);
                s += (fabsf(d1) < 1.0f) ? (0.5f * d1 * d1) : (fabsf(d1) - 0.5f);
                reg_s += s;
            }
        }
    }
    float sums[4] = {nll_s, msk_s, reg_s, pos_s};
#pragma unroll
    for (int k = 0; k < 4; ++k)
#pragma unroll
        for (int off = 32; off > 0; off >>= 1) sums[k] += __shfl_down(sums[k], off);
    if (lane == 0) {
        out[300] = sums[0] / fmaxf(sums[1], 1.0f);
        out[301] = sums[2] / fmaxf(sums[3], 1.0f);
    }
}

extern "C" void kernel_launch(void* const* d_in, const int* in_sizes, int n_in,
                              void* d_out, int out_size, void* d_ws, size_t ws_size,
                              hipStream_t stream) {
    const float* base_feat = (const float*)d_in[0];
    const float* gt        = (const float*)d_in[1];
    const int*   video_len = (const int*)d_in[2];
    const float* w1        = (const float*)d_in[3];
    const float* b1        = (const float*)d_in[4];
    const float* w2        = (const float*)d_in[5];
    const float* b2        = (const float*)d_in[6];
    const float* sw        = (const float*)d_in[7];
    const float* sb        = (const float*)d_in[8];
    const float* dw        = (const float*)d_in[9];
    const float* db        = (const float*)d_in[10];

    char* ws = (char*)d_ws;
    _Float16* w1h = (_Float16*)ws;  ws += (size_t)512 * 6912 * 2;
    _Float16* w1l = (_Float16*)ws;  ws += (size_t)512 * 6912 * 2;
    _Float16* w2h = (_Float16*)ws;  ws += (size_t)512 * 13824 * 2;
    _Float16* w2l = (_Float16*)ws;  ws += (size_t)512 * 13824 * 2;
    _Float16* inh = (_Float16*)ws;  ws += (size_t)65536 * 256 * 2;
    _Float16* inl = (_Float16*)ws;  ws += (size_t)65536 * 256 * 2;
    _Float16* x1h = (_Float16*)ws;  ws += (size_t)64 * 16 * 16 * 512 * 2;
    _Float16* x1l = (_Float16*)ws;  ws += (size_t)64 * 16 * 16 * 512 * 2;
    float* scoreL = (float*)ws;     ws += (size_t)16 * 64 * 4;
    float* deltaL = (float*)ws;     ws += (size_t)16 * 64 * 4;
    float* zpage  = (float*)ws;     ws += (size_t)64 * 4;       // 256B zero page
    // x2p (4, 4096, 512) fp32 = 33.5 MB reuses the inh region (consumed by conv1)
    float* x2p = (float*)inh;

    wt_split_t<<<1024, 256, 0, stream>>>(w1, w1h, w1l, w2, w2h, w2l, zpage);
    in_split<<<dim3(2, 1024), 256, 0, stream>>>(base_feat, inh, inl);
    conv1_mfma<<<dim3(4, 64, 2), 256, 0, stream>>>(inh, inl, w1h, w1l, b1,
                                                   (const _Float16*)zpage, x1h, x1l);
    conv2_mfma<<<dim3(4, 32, 4), 256, 0, stream>>>(x1h, x1l, w2h, w2l,
                                                   (const _Float16*)zpage, x2p);
    feat_head<<<64, 256, 0, stream>>>(x2p, b2, sw, sb, dw, db, scoreL, deltaL);
    nms_loss_kernel<<<1, 64, 0, stream>>>(scoreL, deltaL, gt, video_len,
                                          (float*)d_out);
}

// Round 7
// 769.120 us; speedup vs baseline: 1.3078x; 1.2626x over previous
//
#include <hip/hip_runtime.h>

typedef __attribute__((ext_vector_type(8))) _Float16 half8;
typedef __attribute__((ext_vector_type(4))) _Float16 half4;
typedef __attribute__((ext_vector_type(4))) float floatx4;

#define DI __device__ __forceinline__

DI void gl_lds16(const void* g, void* l) {
    __builtin_amdgcn_global_load_lds(
        (__attribute__((address_space(1))) void*)(g),
        (__attribute__((address_space(3))) void*)(l), 16, 0, 0);
}

// Interleaved layout everywhere: per (row, ci32-block): [32 hi halfs | 32 lo halfs] = 128 B line.

// ------------- weight split -> interleaved (co, tap, cb, hi32|lo32), x64 scale -------------
__global__ __launch_bounds__(256) void wt_split_t(
        const float* __restrict__ w1, _Float16* __restrict__ w1I,
        const float* __restrict__ w2, _Float16* __restrict__ w2I,
        float* __restrict__ zp) {
    __shared__ float L[13824];
    const int b = blockIdx.x;
    const int tid = threadIdx.x;
    if (b == 0 && tid < 64) zp[tid] = 0.0f;      // 256B zero page for conv DMA OOB
    if (b < 512) {
        const float* src = w1 + (size_t)b * 6912;     // [ci=256][tap=27]
        for (int idx = tid; idx < 6912; idx += 256) L[idx] = src[idx] * 64.0f;
        __syncthreads();
        for (int c = tid; c < 864; c += 256) {        // 27 taps x 32 octets
            const int tap = c >> 5, o = c & 31;
            half8 h, l;
#pragma unroll
            for (int j = 0; j < 8; ++j) {
                const float x = L[(o * 8 + j) * 27 + tap];
                const _Float16 hh = (_Float16)x;
                h[j] = hh; l[j] = (_Float16)(x - (float)hh);
            }
            const size_t off = (size_t)b * 13824 + (size_t)(tap * 8 + (o >> 2)) * 64 + (o & 3) * 8;
            *(half8*)&w1I[off] = h;
            *(half8*)&w1I[off + 32] = l;
        }
    } else {
        const float* src = w2 + (size_t)(b - 512) * 13824;   // [ci=512][tap=27]
        for (int idx = tid; idx < 13824; idx += 256) L[idx] = src[idx] * 64.0f;
        __syncthreads();
        for (int c = tid; c < 1728; c += 256) {       // 27 taps x 64 octets
            const int tap = c >> 6, o = c & 63;
            half8 h, l;
#pragma unroll
            for (int j = 0; j < 8; ++j) {
                const float x = L[(o * 8 + j) * 27 + tap];
                const _Float16 hh = (_Float16)x;
                h[j] = hh; l[j] = (_Float16)(x - (float)hh);
            }
            const size_t off = (size_t)(b - 512) * 27648 + (size_t)(tap * 16 + (o >> 2)) * 64 + (o & 3) * 8;
            *(half8*)&w2I[off] = h;
            *(half8*)&w2I[off + 32] = l;
        }
    }
}

// ------------- input split -> interleaved (sp, cb, hi32|lo32): sp*512 + cb*64 -------------
__global__ __launch_bounds__(256) void in_split(const float* __restrict__ in,
                                                _Float16* __restrict__ oI) {
    __shared__ float T[128 * 65];
    const int hb = blockIdx.x;            // ci half: 0,1
    const int s0 = blockIdx.y * 64;       // spatial tile
    const int tid = threadIdx.x;
    const int cil = tid >> 1, part = tid & 1;
    const float* src = in + (size_t)(hb * 128 + cil) * 65536 + s0 + part * 32;
    float v[32];
#pragma unroll
    for (int q = 0; q < 8; ++q) *(float4*)(v + q * 4) = *(const float4*)(src + q * 4);
#pragma unroll
    for (int j = 0; j < 32; ++j) T[cil * 65 + part * 32 + j] = v[j];
    __syncthreads();
#pragma unroll
    for (int k = 0; k < 4; ++k) {         // 64 sp x 16 local octets
        const int c = tid + k * 256;
        const int sp = c >> 4, ol = c & 15;
        half8 h, l;
#pragma unroll
        for (int j = 0; j < 8; ++j) {
            const float x = T[(ol * 8 + j) * 65 + sp];
            const _Float16 hh = (_Float16)x;
            h[j] = hh; l[j] = (_Float16)(x - (float)hh);
        }
        const int og = hb * 16 + ol;
        const size_t off = (size_t)(s0 + sp) * 512 + (size_t)(og >> 2) * 64 + (og & 3) * 8;
        *(half8*)&oI[off] = h;
        *(half8*)&oI[off + 32] = l;
    }
}

// ---------- conv1: dbuf DMA pipeline, K32/iter, interleaved 128B rows ----------
__global__ __launch_bounds__(256, 2) void conv1_mfma(
        const _Float16* __restrict__ xI, const _Float16* __restrict__ wI,
        const float* __restrict__ b1, const _Float16* __restrict__ zp,
        _Float16* __restrict__ yI) {
    __shared__ __align__(16) _Float16 A2[2][128 * 64];
    __shared__ __align__(16) _Float16 B2[2][128 * 64];
    const int tid = threadIdx.x;
    const int co_blk = blockIdx.x;      // 0..3
    const int t = blockIdx.y;           // 0..63
    const int h0 = blockIdx.z * 8;      // 0 or 8
    const int wid = tid >> 6, lane = tid & 63;
    const int wm = wid & 1, wn = wid >> 1;
    const int ml = lane & 15, ql = lane >> 4;
    const int cs0 = (ql ^ (ml & 7)) * 8;          // hi chunk ql
    const int cs1 = ((4 + ql) ^ (ml & 7)) * 8;    // lo chunk ql
    const int sl = lane & 7, rl = lane >> 3;
    const int lc = sl ^ rl;                        // logical chunk (mem offset lc*16B)
    size_t aoff[4]; int dstq[4], ih2[4], iw2[4];
    const size_t wbo = (size_t)co_blk * 128 * 13824;
#pragma unroll
    for (int q = 0; q < 4; ++q) {
        const int row = (q * 4 + wid) * 8 + rl;    // A: co row / B: n row
        aoff[q] = wbo + (size_t)row * 13824 + lc * 8;
        dstq[q] = (q * 4 + wid) * 512 + lane * 8;
        const int h = h0 + (row >> 4), w = row & 15;
        ih2[q] = 2 * h - 1; iw2[q] = 2 * w - 1;
    }

    floatx4 zz = {0.f, 0.f, 0.f, 0.f};
    floatx4 acc[4][4];
#pragma unroll
    for (int i = 0; i < 4; ++i)
#pragma unroll
        for (int j = 0; j < 4; ++j) acc[i][j] = zz;

    auto stage = [&](int kt, int kh, int kw, int cb, int bi) {
        const int tap = (kt * 3 + kh) * 3 + kw;
        const size_t ab = (size_t)(tap * 8 + cb) * 64;
        _Float16* Ad = A2[bi]; _Float16* Bd = B2[bi];
        const int it = t + kt - 1;
        const bool tok = ((unsigned)it < 64u);
#pragma unroll
        for (int q = 0; q < 4; ++q) {
            gl_lds16(wI + aoff[q] + ab, &Ad[dstq[q]]);
            const int ih = ih2[q] + kh, iw = iw2[q] + kw;
            const bool ok = tok && ((unsigned)ih < 32u) && ((unsigned)iw < 32u);
            const _Float16* src = ok
                ? (xI + (size_t)(it * 1024 + ih * 32 + iw) * 512 + cb * 64 + lc * 8)
                : (zp + lc * 8);
            gl_lds16(src, &Bd[dstq[q]]);
        }
    };

    int kt = 0, kh = 0, kw = 0, cb = 0;
    stage(0, 0, 0, 0, 0);
    kw = 1;
    for (int i = 0; i < 216; ++i) {
        __syncthreads();      // drains DMA issued last iter (flew under MFMA phase)
        if (i + 1 < 216) {
            stage(kt, kh, kw, cb, (i + 1) & 1);
            if (++kw == 3) { kw = 0; if (++kh == 3) { kh = 0; if (++kt == 3) { kt = 0; ++cb; } } }
        }
        const _Float16* Ab = A2[i & 1];
        const _Float16* Bb = B2[i & 1];
        half8 ah[4], alo[4], bh8[4], blo[4];
#pragma unroll
        for (int mi = 0; mi < 4; ++mi) {
            ah[mi]  = *(const half8*)&Ab[(wm * 64 + mi * 16 + ml) * 64 + cs0];
            alo[mi] = *(const half8*)&Ab[(wm * 64 + mi * 16 + ml) * 64 + cs1];
        }
#pragma unroll
        for (int ni = 0; ni < 4; ++ni) {
            bh8[ni] = *(const half8*)&Bb[(wn * 64 + ni * 16 + ml) * 64 + cs0];
            blo[ni] = *(const half8*)&Bb[(wn * 64 + ni * 16 + ml) * 64 + cs1];
        }
#pragma unroll
        for (int mi = 0; mi < 4; ++mi)
#pragma unroll
            for (int ni = 0; ni < 4; ++ni) {
                acc[mi][ni] = __builtin_amdgcn_mfma_f32_16x16x32_f16(ah[mi],  bh8[ni], acc[mi][ni], 0, 0, 0);
                acc[mi][ni] = __builtin_amdgcn_mfma_f32_16x16x32_f16(ah[mi],  blo[ni], acc[mi][ni], 0, 0, 0);
                acc[mi][ni] = __builtin_amdgcn_mfma_f32_16x16x32_f16(alo[mi], bh8[ni], acc[mi][ni], 0, 0, 0);
            }
    }

    // epilogue: unscale, +bias, hi/lo split, interleaved store (sp2*1024 + cb*64 + k)
    const int qr = ql * 4;
#pragma unroll
    for (int mi = 0; mi < 4; ++mi) {
        const int co = co_blk * 128 + wm * 64 + mi * 16 + qr;
#pragma unroll
        for (int ni = 0; ni < 4; ++ni) {
            const int n = wn * 64 + ni * 16 + ml;
            const int h = h0 + (n >> 4), w = n & 15;
            const size_t base = ((size_t)t * 256 + h * 16 + w) * 1024
                              + (size_t)(co >> 5) * 64 + (co & 31);
            half4 hv, lv;
#pragma unroll
            for (int r = 0; r < 4; ++r) {
                const float v = acc[mi][ni][r] * 0.015625f + b1[co + r];
                const _Float16 hb = (_Float16)v;
                hv[r] = hb;
                lv[r] = (_Float16)(v - (float)hb);
            }
            *(half4*)(yI + base) = hv;
            *(half4*)(yI + base + 32) = lv;
        }
    }
}

// ---------- conv2: dbuf pipeline, N=128 (2t x 8x8), K-split 4, 108 iters ----------
__global__ __launch_bounds__(256, 2) void conv2_mfma(
        const _Float16* __restrict__ xI, const _Float16* __restrict__ wI,
        const _Float16* __restrict__ zp,
        float* __restrict__ x2p) {
    __shared__ __align__(16) _Float16 A2[2][128 * 64];
    __shared__ __align__(16) _Float16 B2[2][128 * 64];
    const int tid = threadIdx.x;
    const int co_blk = blockIdx.x;      // 0..3
    const int tp = blockIdx.y;          // 0..31
    const int ks = blockIdx.z;          // 0..3
    const int wid = tid >> 6, lane = tid & 63;
    const int wm = wid & 1, wn = wid >> 1;
    const int ml = lane & 15, ql = lane >> 4;
    const int cs0 = (ql ^ (ml & 7)) * 8;
    const int cs1 = ((4 + ql) ^ (ml & 7)) * 8;
    const int sl = lane & 7, rl = lane >> 3;
    const int lc = sl ^ rl;
    size_t aoff[4]; int dstq[4], ih2[4], iw2[4], tl4[4];
    const size_t wbo = (size_t)co_blk * 128 * 27648;
#pragma unroll
    for (int q = 0; q < 4; ++q) {
        const int row = (q * 4 + wid) * 8 + rl;
        aoff[q] = wbo + (size_t)row * 27648 + lc * 8;
        dstq[q] = (q * 4 + wid) * 512 + lane * 8;
        const int sp = row & 63;
        tl4[q] = row >> 6;
        ih2[q] = 2 * (sp >> 3) - 1; iw2[q] = 2 * (sp & 7) - 1;
    }

    floatx4 zz = {0.f, 0.f, 0.f, 0.f};
    floatx4 acc[4][4];
#pragma unroll
    for (int i = 0; i < 4; ++i)
#pragma unroll
        for (int j = 0; j < 4; ++j) acc[i][j] = zz;

    auto stage = [&](int kt, int kh, int kw, int cb, int bi) {
        const int tap = (kt * 3 + kh) * 3 + kw;
        const size_t ab = (size_t)(tap * 16 + cb) * 64;
        _Float16* Ad = A2[bi]; _Float16* Bd = B2[bi];
#pragma unroll
        for (int q = 0; q < 4; ++q) {
            gl_lds16(wI + aoff[q] + ab, &Ad[dstq[q]]);
            const int it = tp * 2 + tl4[q] + kt - 1;
            const int ih = ih2[q] + kh, iw = iw2[q] + kw;
            const bool ok = ((unsigned)it < 64u) && ((unsigned)ih < 16u) && ((unsigned)iw < 16u);
            const _Float16* src = ok
                ? (xI + (size_t)(it * 256 + ih * 16 + iw) * 1024 + cb * 64 + lc * 8)
                : (zp + lc * 8);
            gl_lds16(src, &Bd[dstq[q]]);
        }
    };

    int kt = 0, kh = 0, kw = 0, cb = ks * 4;
    stage(0, 0, 0, cb, 0);
    kw = 1;
    for (int i = 0; i < 108; ++i) {
        __syncthreads();
        if (i + 1 < 108) {
            stage(kt, kh, kw, cb, (i + 1) & 1);
            if (++kw == 3) { kw = 0; if (++kh == 3) { kh = 0; if (++kt == 3) { kt = 0; ++cb; } } }
        }
        const _Float16* Ab = A2[i & 1];
        const _Float16* Bb = B2[i & 1];
        half8 ah[4], alo[4], bh8[4], blo[4];
#pragma unroll
        for (int mi = 0; mi < 4; ++mi) {
            ah[mi]  = *(const half8*)&Ab[(wm * 64 + mi * 16 + ml) * 64 + cs0];
            alo[mi] = *(const half8*)&Ab[(wm * 64 + mi * 16 + ml) * 64 + cs1];
        }
#pragma unroll
        for (int ni = 0; ni < 4; ++ni) {
            bh8[ni] = *(const half8*)&Bb[(wn * 64 + ni * 16 + ml) * 64 + cs0];
            blo[ni] = *(const half8*)&Bb[(wn * 64 + ni * 16 + ml) * 64 + cs1];
        }
#pragma unroll
        for (int mi = 0; mi < 4; ++mi)
#pragma unroll
            for (int ni = 0; ni < 4; ++ni) {
                acc[mi][ni] = __builtin_amdgcn_mfma_f32_16x16x32_f16(ah[mi],  bh8[ni], acc[mi][ni], 0, 0, 0);
                acc[mi][ni] = __builtin_amdgcn_mfma_f32_16x16x32_f16(ah[mi],  blo[ni], acc[mi][ni], 0, 0, 0);
                acc[mi][ni] = __builtin_amdgcn_mfma_f32_16x16x32_f16(alo[mi], bh8[ni], acc[mi][ni], 0, 0, 0);
            }
    }

    const int qr = ql * 4;
#pragma unroll
    for (int mi = 0; mi < 4; ++mi) {
        const int co = co_blk * 128 + wm * 64 + mi * 16 + qr;
#pragma unroll
        for (int ni = 0; ni < 4; ++ni) {
            const int n = wn * 64 + ni * 16 + ml;
            const int ng = tp * 128 + n;
            float4 v;
            v.x = acc[mi][ni][0]; v.y = acc[mi][ni][1];
            v.z = acc[mi][ni][2]; v.w = acc[mi][ni][3];
            *(float4*)&x2p[((size_t)ks * 4096 + ng) * 512 + co] = v;
        }
    }
}

// ------------- fused feat (K-split sum + spatial max + bias) and head matvec -------------
__global__ __launch_bounds__(256) void feat_head(
        const float* __restrict__ x2p, const float* __restrict__ b2,
        const float* __restrict__ sw, const float* __restrict__ sb,
        const float* __restrict__ dw, const float* __restrict__ db,
        float* __restrict__ scoreL, float* __restrict__ deltaL) {
    __shared__ float fr[512];
    __shared__ float partial[32][8];
    const int t = blockIdx.x, tid = threadIdx.x;
#pragma unroll
    for (int cc = 0; cc < 2; ++cc) {
        const int c = tid + cc * 256;
        float mx = -3.4e38f;
        for (int sp = 0; sp < 64; ++sp) {
            const size_t ng = (size_t)t * 64 + sp;
            const float s = x2p[ng * 512 + c]
                          + x2p[((size_t)4096 + ng) * 512 + c]
                          + x2p[((size_t)8192 + ng) * 512 + c]
                          + x2p[((size_t)12288 + ng) * 512 + c];
            mx = fmaxf(mx, s);
        }
        fr[c] = mx * 0.015625f + b2[c];
    }
    __syncthreads();
    const int o = tid & 31, part = tid >> 5;
    const float* wrow = (o < 16) ? (sw + (size_t)o * 512) : (dw + (size_t)(o - 16) * 512);
    float s = 0.f;
    const int j0 = part * 64;
#pragma unroll 16
    for (int j = 0; j < 64; ++j) s += wrow[j0 + j] * fr[j0 + j];
    partial[o][part] = s;
    __syncthreads();
    if (tid < 32) {
        float tot = 0.f;
#pragma unroll
        for (int p = 0; p < 8; ++p) tot += partial[tid][p];
        tot += (tid < 16) ? sb[tid] : db[tid - 16];
        if (tid < 16) scoreL[tid * 64 + t] = tot;
        else deltaL[(tid - 16) * 64 + t] = tot;
    }
}

// ------------- NMS + labels + losses: SINGLE WAVE (64 lanes), no barriers -------------
__global__ void nms_loss_kernel(const float* __restrict__ scoreL,
                                const float* __restrict__ deltaL,
                                const float* __restrict__ gt,
                                const int* __restrict__ video_len,
                                float* __restrict__ out) {
    const int lane = threadIdx.x & 63;
    float gsv[8], gev[8];
#pragma unroll
    for (int g = 0; g < 8; ++g) { gsv[g] = gt[2 * g]; gev[g] = gt[2 * g + 1]; }
    const float center = ((float)lane + 0.5f) * 8.0f;
    float psv[8], pev[8], fg[8], l0v[8], l1v[8], dcv[8], dlv[8];
#pragma unroll
    for (int j = 0; j < 8; ++j) {
        const float s0 = scoreL[j * 64 + lane], s1 = scoreL[(8 + j) * 64 + lane];
        const float mm = fmaxf(s0, s1);
        const float lse = mm + logf(expf(s0 - mm) + expf(s1 - mm));
        l0v[j] = s0 - lse; l1v[j] = s1 - lse;
        const float dc = deltaL[j * 64 + lane], dl = deltaL[(8 + j) * 64 + lane];
        dcv[j] = dc; dlv[j] = dl;
        const float alen = 8.0f * (float)(1 << j);
        const float pc = center + dc * alen;
        const float pl = alen * expf(fminf(fmaxf(dl, -10.0f), 10.0f));
        const float ps = fminf(fmaxf(pc - pl * 0.5f, 0.0f), 512.0f);
        const float pe = fminf(fmaxf(pc + pl * 0.5f, 0.0f), 512.0f);
        psv[j] = ps; pev[j] = pe;
        fg[j] = ((pe - ps) >= 4.0f) ? expf(l1v[j]) : -1e9f;
    }
    for (int itn = 0; itn < 100; ++itn) {
        float v = fg[0]; int idx = lane;
#pragma unroll
        for (int j = 1; j < 8; ++j) if (fg[j] > v) { v = fg[j]; idx = lane + 64 * j; }
#pragma unroll
        for (int off = 32; off > 0; off >>= 1) {
            const float ov = __shfl_down(v, off);
            const int oi = __shfl_down(idx, off);
            if (ov > v || (ov == v && oi < idx)) { v = ov; idx = oi; }
        }
        v = __shfl(v, 0); idx = __shfl(idx, 0);
        const int wj = idx >> 6, wl = idx & 63;
        float bw0 = 0.f, bw1 = 0.f;
#pragma unroll
        for (int j = 0; j < 8; ++j) if (j == wj) { bw0 = psv[j]; bw1 = pev[j]; }
        const float b0 = __shfl(bw0, wl);
        const float b1 = __shfl(bw1, wl);
        if (lane == 0) {
            const bool kept = v > -5e8f;
            out[2 * itn] = kept ? b0 : 0.0f;
            out[2 * itn + 1] = kept ? b1 : 0.0f;
            out[200 + itn] = kept ? v : 0.0f;
        }
#pragma unroll
        for (int j = 0; j < 8; ++j) {
            const int n = lane + 64 * j;
            const float inter = fmaxf(fminf(b1, pev[j]) - fmaxf(b0, psv[j]), 0.0f);
            const float uni = (b1 - b0) + (pev[j] - psv[j]) - inter;
            const float iou = inter / fmaxf(uni, 1e-6f);
            if (iou > 0.7f || n == idx) fg[j] = -1e9f;
        }
    }
    int labv[8], aggv[8];
#pragma unroll
    for (int j = 0; j < 8; ++j) {
        const float alen = 8.0f * (float)(1 << j);
        const float as_ = center - alen * 0.5f, ae_ = center + alen * 0.5f;
        float mx = -1.0f; int ag = 0;
#pragma unroll
        for (int g = 0; g < 8; ++g) {
            const float inter = fmaxf(fminf(ae_, gev[g]) - fmaxf(as_, gsv[g]), 0.0f);
            const float uni = (ae_ - as_) + (gev[g] - gsv[g]) - inter;
            const float iou = inter / fmaxf(uni, 1e-6f);
            if (iou > mx) { mx = iou; ag = g; }
        }
        labv[j] = (mx < 0.3f) ? 0 : ((mx >= 0.7f) ? 1 : -1);
        aggv[j] = ag;
    }
    for (int g = 0; g < 8; ++g) {
        float v = -1.0f; int idx = 0;
#pragma unroll
        for (int j = 0; j < 8; ++j) {
            const int n = lane + 64 * j;
            const float alen = 8.0f * (float)(1 << j);
            const float as_ = center - alen * 0.5f, ae_ = center + alen * 0.5f;
            const float inter = fmaxf(fminf(ae_, gev[g]) - fmaxf(as_, gsv[g]), 0.0f);
            const float uni = (ae_ - as_) + (gev[g] - gsv[g]) - inter;
            const float iou = inter / fmaxf(uni, 1e-6f);
            if (iou > v || (iou == v && n < idx)) { v = iou; idx = n; }
        }
#pragma unroll
        for (int off = 32; off > 0; off >>= 1) {
            const float ov = __shfl_down(v, off);
            const int oi = __shfl_down(idx, off);
            if (ov > v || (ov == v && oi < idx)) { v = ov; idx = oi; }
        }
        idx = __shfl(idx, 0);
#pragma unroll
        for (int j = 0; j < 8; ++j)
            if (lane == (idx & 63) && j == (idx >> 6)) labv[j] = 1;
    }
    const float vl = (float)video_len[0];
    float nll_s = 0.f, msk_s = 0.f, reg_s = 0.f, pos_s = 0.f;
#pragma unroll
    for (int j = 0; j < 8; ++j) {
        const float alen = 8.0f * (float)(1 << j);
        const float as_ = center - alen * 0.5f, ae_ = center + alen * 0.5f;
        int l = labv[j];
        if (!((as_ >= 0.0f) && (ae_ <= vl))) l = -1;
        if (l >= 0) {
            msk_s += 1.0f;
            nll_s -= (l == 1) ? l1v[j] : l0v[j];
            if (l == 1) {
                pos_s += 1.0f;
                float gcv = 0.f, glv = 0.f;
#pragma unroll
                for (int g = 0; g < 8; ++g)
                    if (g == aggv[j]) {
                        gcv = (gsv[g] + gev[g]) * 0.5f;
                        glv = fmaxf(gev[g] - gsv[g], 1e-6f);
                    }
                const float r0 = (gcv - center) / alen;
                const float r1 = logf(glv / alen);
                const float d0 = dcv[j] - r0, d1 = dlv[j] - r1;
                float s = (fabsf(d0) < 1.0f) ? (0.5f * d0 * d0) : (fabsf(d0) - 0.5f);
                s += (fabsf(d1) < 1.0f) ? (0.5f * d1 * d1) : (fabsf(d1) - 0.5f);
                reg_s += s;
            }
        }
    }
    float sums[4] = {nll_s, msk_s, reg_s, pos_s};
#pragma unroll
    for (int k = 0; k < 4; ++k)
#pragma unroll
        for (int off = 32; off > 0; off >>= 1) sums[k] += __shfl_down(sums[k], off);
    if (lane == 0) {
        out[300] = sums[0] / fmaxf(sums[1], 1.0f);
        out[301] = sums[2] / fmaxf(sums[3], 1.0f);
    }
}

extern "C" void kernel_launch(void* const* d_in, const int* in_sizes, int n_in,
                              void* d_out, int out_size, void* d_ws, size_t ws_size,
                              hipStream_t stream) {
    const float* base_feat = (const float*)d_in[0];
    const float* gt        = (const float*)d_in[1];
    const int*   video_len = (const int*)d_in[2];
    const float* w1        = (const float*)d_in[3];
    const float* b1        = (const float*)d_in[4];
    const float* w2        = (const float*)d_in[5];
    const float* b2        = (const float*)d_in[6];
    const float* sw        = (const float*)d_in[7];
    const float* sb        = (const float*)d_in[8];
    const float* dw        = (const float*)d_in[9];
    const float* db        = (const float*)d_in[10];

    char* ws = (char*)d_ws;
    _Float16* w1I = (_Float16*)ws;  ws += (size_t)512 * 13824 * 2;   // 14.2 MB
    _Float16* w2I = (_Float16*)ws;  ws += (size_t)512 * 27648 * 2;   // 28.3 MB
    _Float16* inI = (_Float16*)ws;  ws += (size_t)65536 * 512 * 2;   // 67.1 MB
    _Float16* x1I = (_Float16*)ws;  ws += (size_t)16384 * 1024 * 2;  // 33.5 MB
    float* scoreL = (float*)ws;     ws += (size_t)16 * 64 * 4;
    float* deltaL = (float*)ws;     ws += (size_t)16 * 64 * 4;
    float* zpage  = (float*)ws;     ws += (size_t)64 * 4;            // 256B zero page
    // x2p (4, 4096, 512) fp32 = 33.5 MB reuses the inI region (consumed by conv1)
    float* x2p = (float*)inI;

    wt_split_t<<<1024, 256, 0, stream>>>(w1, w1I, w2, w2I, zpage);
    in_split<<<dim3(2, 1024), 256, 0, stream>>>(base_feat, inI);
    conv1_mfma<<<dim3(4, 64, 2), 256, 0, stream>>>(inI, w1I, b1,
                                                   (const _Float16*)zpage, x1I);
    conv2_mfma<<<dim3(4, 32, 4), 256, 0, stream>>>(x1I, w2I,
                                                   (const _Float16*)zpage, x2p);
    feat_head<<<64, 256, 0, stream>>>(x2p, b2, sw, sb, dw, db, scoreL, deltaL);
    nms_loss_kernel<<<1, 64, 0, stream>>>(scoreL, deltaL, gt, video_len,
                                          (float*)d_out);
}